// Round 6
// baseline (899.917 us; speedup 1.0000x reference)
//
#include <hip/hip_runtime.h>
#include <hip/hip_bf16.h>
#include <stdint.h>

#define NNODES 100000
#define DF 64
#define NEDGES 1600000
#define ND (NNODES * DF)     // 6,400,000
#define BKT 100              // targets per bucket
#define NBUCK 1000           // BKT*NBUCK == NNODES exactly

// ---------- helpers ----------
static __device__ __forceinline__ float bf2f(unsigned short u) {
    union { uint32_t i; float f; } c; c.i = ((uint32_t)u) << 16; return c.f;
}
static __device__ __forceinline__ void unpack2(uint32_t u, float& lo, float& hi) {
    union { uint32_t i; float f; } a, b;
    a.i = u << 16; b.i = u & 0xFFFF0000u;
    lo = a.f; hi = b.f;
}

// ---------- dtype detector: flags[0]=bf16?, flags[1]=int64? ----------
__global__ void detect_k(const unsigned short* __restrict__ x,
                         const unsigned int* __restrict__ ei,
                         int* __restrict__ flags) {
    __shared__ int cnt_sane, cnt_odd_nz;
    if (threadIdx.x == 0) { cnt_sane = 0; cnt_odd_nz = 0; }
    __syncthreads();
    unsigned short s = x[threadIdx.x * 2];
    unsigned short m = s & 0x7FFF;
    if (m < 0x0080 || (m >= 0x3000 && m <= 0x4200)) atomicAdd(&cnt_sane, 1);
    if (threadIdx.x < 64) {
        if (ei[threadIdx.x * 2 + 1] != 0u) atomicAdd(&cnt_odd_nz, 1);
    }
    __syncthreads();
    if (threadIdx.x == 0) {
        flags[0] = (cnt_sane >= 192) ? 1 : 0;
        flags[1] = (cnt_odd_nz == 0) ? 1 : 0;
    }
}

// ---------- weight canonicalization -> fp32 ----------
// WfM/WfU: [128][64]; row j<64 = W[:, :64] row j ; row j>=64 = W[:, 64:] row j-64
// prm: b_msg[0:64) | b_upd[64:128) | gamma[128:192) | beta[192:256)
__global__ void wconv_k(const int* __restrict__ flags,
                        const void* __restrict__ Wm, const void* __restrict__ Wu,
                        const void* __restrict__ bm, const void* __restrict__ bu,
                        const void* __restrict__ ga, const void* __restrict__ be,
                        float* __restrict__ WfM, float* __restrict__ WfU,
                        float* __restrict__ prm) {
    const int bf = flags[0];
    int i = blockIdx.x * 256 + threadIdx.x;
    if (i < 16384) {
        const void* src = (i < 8192) ? Wm : Wu;
        float* dst = (i < 8192) ? WfM : WfU;
        int ii = i & 8191, j = ii >> 6, k = ii & 63;
        int si = (j & 63) * 128 + ((j >> 6) ? 64 : 0) + k;
        dst[ii] = bf ? bf2f(((const unsigned short*)src)[si]) : ((const float*)src)[si];
    } else if (i < 16384 + 256) {
        int t = i - 16384, which = t >> 6, k = t & 63;
        const void* p = (which == 0) ? bm : (which == 1) ? bu : (which == 2) ? ga : be;
        prm[t] = bf ? bf2f(((const unsigned short*)p)[k]) : ((const float*)p)[k];
    }
}

// ---------- projection: Ps = x@Wm_s^T ; Pt = x@Wm_t^T + b_msg  (bf16 out) ----------
__global__ __launch_bounds__(256) void proj_k(const int* __restrict__ flags,
                                              const void* __restrict__ xv,
                                              const float* __restrict__ WfM,
                                              const float* __restrict__ prm,
                                              __hip_bfloat16* __restrict__ Ps,
                                              __hip_bfloat16* __restrict__ Pt) {
    const int bf = flags[0];
    const int lane = threadIdx.x & 63;
    const int wib = __builtin_amdgcn_readfirstlane(threadIdx.x >> 6);

    float wsr[64], wtr[64];
    {
        const float* r0 = WfM + lane * 64;          // Wm_s row `lane`
        const float* r1 = WfM + (64 + lane) * 64;   // Wm_t row `lane`
        #pragma unroll
        for (int k = 0; k < 64; ++k) { wsr[k] = r0[k]; wtr[k] = r1[k]; }
    }
    const float bm = prm[lane];

    for (int n = blockIdx.x * 4 + wib; n < NNODES; n += gridDim.x * 4) {
        float as0 = 0.f, as1 = 0.f, at0 = 0.f, at1 = 0.f;
        if (bf) {
            const uint32_t* xw = (const uint32_t*)((const unsigned short*)xv + (size_t)n * DF);
            #pragma unroll
            for (int d = 0; d < 32; ++d) {
                float x0, x1; unpack2(xw[d], x0, x1);
                as0 = fmaf(x0, wsr[2*d],   as0);
                as1 = fmaf(x1, wsr[2*d+1], as1);
                at0 = fmaf(x0, wtr[2*d],   at0);
                at1 = fmaf(x1, wtr[2*d+1], at1);
            }
        } else {
            const float* xf = (const float*)xv + (size_t)n * DF;
            #pragma unroll
            for (int d = 0; d < 64; d += 2) {
                as0 = fmaf(xf[d],   wsr[d],   as0);
                as1 = fmaf(xf[d+1], wsr[d+1], as1);
                at0 = fmaf(xf[d],   wtr[d],   at0);
                at1 = fmaf(xf[d+1], wtr[d+1], at1);
            }
        }
        Ps[(size_t)n * DF + lane] = __float2bfloat16(as0 + as1);
        Pt[(size_t)n * DF + lane] = __float2bfloat16(at0 + at1 + bm);
    }
}

// ---------- bucket histogram (LDS pre-aggregated) ----------
__global__ __launch_bounds__(256) void bhist_k(const int* __restrict__ flags,
                                               const int* __restrict__ ei,
                                               int* __restrict__ BktCnt) {
    __shared__ int h[NBUCK];
    const int i64 = flags[1];
    for (int i = threadIdx.x; i < NBUCK; i += 256) h[i] = 0;
    __syncthreads();
    int stride = gridDim.x * 256;
    for (int e = blockIdx.x * 256 + threadIdx.x; e < NEDGES; e += stride) {
        int tgt = i64 ? ei[4*e + 2] : ei[2*e + 1];
        if ((unsigned)tgt < NNODES) atomicAdd(&h[tgt / BKT], 1);
    }
    __syncthreads();
    for (int b = threadIdx.x; b < NBUCK; b += 256)
        if (h[b]) atomicAdd(BktCnt + b, h[b]);
}

// ---------- scan of 1000 bucket counts ----------
__global__ __launch_bounds__(1024) void bscan_k(const int* __restrict__ BktCnt,
                                                int* __restrict__ BktOff,
                                                int* __restrict__ BktCur) {
    __shared__ int lds[1024];
    int t = threadIdx.x;
    int c = (t < NBUCK) ? BktCnt[t] : 0;
    lds[t] = c;
    __syncthreads();
    for (int off = 1; off < 1024; off <<= 1) {
        int add = (t >= off) ? lds[t - off] : 0;
        __syncthreads();
        lds[t] += add;
        __syncthreads();
    }
    if (t < NBUCK) {
        int ex = lds[t] - c;
        BktOff[t] = ex;
        BktCur[t] = ex;
    }
    if (t == NBUCK - 1) BktOff[NBUCK] = lds[t];
}

// ---------- bucket fill: two-pass slice binning, packed 4B payload ----------
__global__ __launch_bounds__(256) void bfill_k(const int* __restrict__ flags,
                                               const int* __restrict__ ei,
                                               int* __restrict__ BktCur,
                                               int* __restrict__ BktE) {
    __shared__ int h[NBUCK], h2[NBUCK], basee[NBUCK];
    const int i64 = flags[1];
    for (int i = threadIdx.x; i < NBUCK; i += 256) { h[i] = 0; h2[i] = 0; }
    __syncthreads();
    const int stride = gridDim.x * 256;
    // pass A: count
    for (int e = blockIdx.x * 256 + threadIdx.x; e < NEDGES; e += stride) {
        int tgt = i64 ? ei[4*e + 2] : ei[2*e + 1];
        if ((unsigned)tgt < NNODES) atomicAdd(&h[tgt / BKT], 1);
    }
    __syncthreads();
    // reserve contiguous runs per bucket
    for (int b = threadIdx.x; b < NBUCK; b += 256)
        if (h[b]) basee[b] = atomicAdd(BktCur + b, h[b]);
    __syncthreads();
    // pass B: write packed (tl<<24 | src)
    for (int e = blockIdx.x * 256 + threadIdx.x; e < NEDGES; e += stride) {
        int src, tgt;
        if (i64) { src = ei[4*e]; tgt = ei[4*e + 2]; }
        else     { src = ei[2*e]; tgt = ei[2*e + 1]; }
        if ((unsigned)tgt >= NNODES) continue;
        int b = tgt / BKT;
        int tl = tgt - b * BKT;
        int r = atomicAdd(&h2[b], 1);
        BktE[basee[b] + r] = (tl << 24) | (src & 0xFFFFFF);
    }
}

// ---------- bucket aggregation: LDS fp32 accumulate, one coalesced flush ----------
__global__ __launch_bounds__(256, 4) void bagg_k(const int* __restrict__ BktOff,
                                                 const int* __restrict__ BktE,
                                                 const __hip_bfloat16* __restrict__ Ps,
                                                 const __hip_bfloat16* __restrict__ Pt,
                                                 __hip_bfloat16* __restrict__ Msg) {
    __shared__ float MsgS[BKT * DF];          // 25.6 KB
    __shared__ unsigned short PtB[BKT * DF];  // 12.8 KB
    __shared__ int cntS[BKT];
    const int tid = threadIdx.x;
    const int lane = tid & 63;
    const int wv = tid >> 6;
    const int b = blockIdx.x;
    const int t0 = b * BKT;

    for (int i = tid; i < BKT * DF; i += 256) MsgS[i] = 0.f;
    for (int i = tid; i < BKT; i += 256) cntS[i] = 0;
    {   // stage Pt slice (contiguous) into LDS, 4B per lane
        const uint32_t* sp = (const uint32_t*)(Pt + (size_t)t0 * DF);
        uint32_t* dp = (uint32_t*)PtB;
        for (int i = tid; i < BKT * DF / 2; i += 256) dp[i] = sp[i];
    }
    __syncthreads();

    const int s = BktOff[b], e = BktOff[b + 1];
    const unsigned short* Ps16 = (const unsigned short*)Ps;

    for (int base = s + wv * 64; base < e; base += 256) {
        int nk = e - base; if (nk > 64) nk = 64;
        int v = (base + lane < e) ? BktE[base + lane] : 0;
        int k = 0;
        for (; k + 4 <= nk; k += 4) {
            int v0 = __shfl(v, k,     64);
            int v1 = __shfl(v, k + 1, 64);
            int v2 = __shfl(v, k + 2, 64);
            int v3 = __shfl(v, k + 3, 64);
            int s0 = v0 & 0xFFFFFF, s1 = v1 & 0xFFFFFF, s2 = v2 & 0xFFFFFF, s3 = v3 & 0xFFFFFF;
            if (s0 >= NNODES) s0 = 0;
            if (s1 >= NNODES) s1 = 0;
            if (s2 >= NNODES) s2 = 0;
            if (s3 >= NNODES) s3 = 0;
            int t1 = ((unsigned)v0) >> 24, t2 = ((unsigned)v1) >> 24;
            int t3 = ((unsigned)v2) >> 24, t4 = ((unsigned)v3) >> 24;
            float p0 = bf2f(Ps16[(size_t)s0 * DF + lane]);   // 4 gathers in flight
            float p1 = bf2f(Ps16[(size_t)s1 * DF + lane]);
            float p2 = bf2f(Ps16[(size_t)s2 * DF + lane]);
            float p3 = bf2f(Ps16[(size_t)s3 * DF + lane]);
            float q0 = bf2f(PtB[t1 * DF + lane]);
            float q1 = bf2f(PtB[t2 * DF + lane]);
            float q2 = bf2f(PtB[t3 * DF + lane]);
            float q3 = bf2f(PtB[t4 * DF + lane]);
            atomicAdd(&MsgS[t1 * DF + lane], fmaxf(p0 + q0, 0.f));
            atomicAdd(&MsgS[t2 * DF + lane], fmaxf(p1 + q1, 0.f));
            atomicAdd(&MsgS[t3 * DF + lane], fmaxf(p2 + q2, 0.f));
            atomicAdd(&MsgS[t4 * DF + lane], fmaxf(p3 + q3, 0.f));
            if (lane == 0) {
                atomicAdd(&cntS[t1], 1); atomicAdd(&cntS[t2], 1);
                atomicAdd(&cntS[t3], 1); atomicAdd(&cntS[t4], 1);
            }
        }
        for (; k < nk; ++k) {
            int v0 = __shfl(v, k, 64);
            int s0 = v0 & 0xFFFFFF;
            if (s0 >= NNODES) s0 = 0;
            int t1 = ((unsigned)v0) >> 24;
            float p0 = bf2f(Ps16[(size_t)s0 * DF + lane]);
            float q0 = bf2f(PtB[t1 * DF + lane]);
            atomicAdd(&MsgS[t1 * DF + lane], fmaxf(p0 + q0, 0.f));
            if (lane == 0) atomicAdd(&cntS[t1], 1);
        }
    }
    __syncthreads();

    // mean + coalesced bf16 flush
    for (int i = tid; i < BKT * DF; i += 256) {
        int c = cntS[i >> 6];
        float inv = 1.0f / (float)(c > 0 ? c : 1);
        Msg[(size_t)t0 * DF + i] = __float2bfloat16(MsgS[i] * inv);
    }
}

// ---------- update + residual + LayerNorm ----------
__global__ __launch_bounds__(256) void upd_k(const int* __restrict__ flags,
                                             const void* __restrict__ xv,
                                             const __hip_bfloat16* __restrict__ Msg,
                                             const float* __restrict__ WfU,
                                             const float* __restrict__ prm,
                                             void* __restrict__ outv) {
    const int bf = flags[0];
    const int lane = threadIdx.x & 63;
    const int wib = __builtin_amdgcn_readfirstlane(threadIdx.x >> 6);

    float wx[64], wm[64];
    {
        const float* r0 = WfU + lane * 64;          // Wu_x row `lane`
        const float* r1 = WfU + (lane + 64) * 64;   // Wu_m row `lane`
        #pragma unroll
        for (int k = 0; k < 64; ++k) { wx[k] = r0[k]; wm[k] = r1[k]; }
    }
    const float bu = prm[64 + lane];
    const float ga = prm[128 + lane];
    const float be = prm[192 + lane];

    for (int n = blockIdx.x * 4 + wib; n < NNODES; n += gridDim.x * 4) {
        float da0 = 0.f, da1 = 0.f, db0 = 0.f, db1 = 0.f;
        float xl;
        if (bf) {
            const uint32_t* xw = (const uint32_t*)((const unsigned short*)xv + (size_t)n * DF);
            #pragma unroll
            for (int d = 0; d < 32; ++d) {
                float x0, x1; unpack2(xw[d], x0, x1);
                da0 = fmaf(x0, wx[2*d],   da0);
                da1 = fmaf(x1, wx[2*d+1], da1);
            }
            xl = bf2f(((const unsigned short*)xv)[(size_t)n * DF + lane]);
        } else {
            const float* xf = (const float*)xv + (size_t)n * DF;
            #pragma unroll
            for (int d = 0; d < 64; d += 2) {
                da0 = fmaf(xf[d],   wx[d],   da0);
                da1 = fmaf(xf[d+1], wx[d+1], da1);
            }
            xl = ((const float*)xv)[(size_t)n * DF + lane];
        }
        {
            const uint32_t* mw = (const uint32_t*)((const unsigned short*)Msg + (size_t)n * DF);
            #pragma unroll
            for (int d = 0; d < 32; ++d) {
                float m0, m1; unpack2(mw[d], m0, m1);
                db0 = fmaf(m0, wm[2*d],   db0);
                db1 = fmaf(m1, wm[2*d+1], db1);
            }
        }
        float u = fmaxf((da0 + da1) + (db0 + db1) + bu, 0.f);
        float r = u + xl;

        float s = r, s2 = r * r;
        #pragma unroll
        for (int m = 1; m < 64; m <<= 1) {
            s  += __shfl_xor(s, m, 64);
            s2 += __shfl_xor(s2, m, 64);
        }
        float mu  = s * (1.0f / 64.0f);
        float var = fmaxf(s2 * (1.0f / 64.0f) - mu * mu, 0.f);
        float o = (r - mu) * rsqrtf(var + 1e-5f) * ga + be;

        size_t gi = (size_t)n * DF + lane;
        if (bf) ((__hip_bfloat16*)outv)[gi] = __float2bfloat16(o);
        else    ((float*)outv)[gi] = o;
    }
}

extern "C" void kernel_launch(void* const* d_in, const int* in_sizes, int n_in,
                              void* d_out, int out_size, void* d_ws, size_t ws_size,
                              hipStream_t stream) {
    const void* x  = d_in[0];
    const int*  ei = (const int*)d_in[1];
    const void* Wm = d_in[2];
    const void* bm = d_in[3];
    const void* Wu = d_in[4];
    const void* bu = d_in[5];
    const void* ga = d_in[6];
    const void* be = d_in[7];

    char* ws = (char*)d_ws;
    size_t off = 0;
    __hip_bfloat16* Ps  = (__hip_bfloat16*)(ws + off); off += (size_t)ND * 2;   // 12.8 MB
    __hip_bfloat16* Pt  = (__hip_bfloat16*)(ws + off); off += (size_t)ND * 2;   // 12.8 MB
    __hip_bfloat16* Msg = (__hip_bfloat16*)(ws + off); off += (size_t)ND * 2;   // 12.8 MB
    int*   BktE   = (int*)(ws + off); off += (size_t)NEDGES * 4;                // 6.4 MB
    int*   BktCnt = (int*)(ws + off); off += NBUCK * 4;                         // memset 0
    int*   BktOff = (int*)(ws + off); off += (NBUCK + 1) * 4;
    int*   BktCur = (int*)(ws + off); off += NBUCK * 4;
    int*   flg    = (int*)(ws + off); off += 16;
    float* WfM    = (float*)(ws + off); off += 8192 * 4;
    float* WfU    = (float*)(ws + off); off += 8192 * 4;
    float* prm    = (float*)(ws + off); off += 256 * 4;

    (void)hipMemsetAsync(BktCnt, 0, NBUCK * 4, stream);

    detect_k<<<1, 256, 0, stream>>>((const unsigned short*)x, (const unsigned int*)ei, flg);
    wconv_k<<<65, 256, 0, stream>>>(flg, Wm, Wu, bm, bu, ga, be, WfM, WfU, prm);

    proj_k<<<391, 256, 0, stream>>>(flg, x, WfM, prm, Ps, Pt);

    bhist_k<<<256, 256, 0, stream>>>(flg, ei, BktCnt);
    bscan_k<<<1, 1024, 0, stream>>>(BktCnt, BktOff, BktCur);
    bfill_k<<<256, 256, 0, stream>>>(flg, ei, BktCur, BktE);

    bagg_k<<<NBUCK, 256, 0, stream>>>(BktOff, BktE, Ps, Pt, Msg);

    upd_k<<<391, 256, 0, stream>>>(flg, x, Msg, WfU, prm, d_out);
}

// Round 7
// 379.603 us; speedup vs baseline: 2.3707x; 2.3707x over previous
//
#include <hip/hip_runtime.h>
#include <hip/hip_bf16.h>
#include <stdint.h>

#define NNODES 100000
#define DF 64
#define NEDGES 1600000
#define ND (NNODES * DF)     // 6,400,000
#define BKT 100              // targets per bucket
#define NBUCK 1000           // BKT*NBUCK == NNODES
#define CHUNK 128            // edges per wave in agg_k
#define NCHUNK (NEDGES / CHUNK)   // 12500

// ---------- helpers ----------
static __device__ __forceinline__ float bf2f(unsigned short u) {
    union { uint32_t i; float f; } c; c.i = ((uint32_t)u) << 16; return c.f;
}
static __device__ __forceinline__ void unpack2(uint32_t u, float& lo, float& hi) {
    union { uint32_t i; float f; } a, b;
    a.i = u << 16; b.i = u & 0xFFFF0000u;
    lo = a.f; hi = b.f;
}

// ---------- dtype detector: flags[0]=bf16?, flags[1]=int64? ----------
__global__ void detect_k(const unsigned short* __restrict__ x,
                         const unsigned int* __restrict__ ei,
                         int* __restrict__ flags) {
    __shared__ int cnt_sane, cnt_odd_nz;
    if (threadIdx.x == 0) { cnt_sane = 0; cnt_odd_nz = 0; }
    __syncthreads();
    unsigned short s = x[threadIdx.x * 2];
    unsigned short m = s & 0x7FFF;
    if (m < 0x0080 || (m >= 0x3000 && m <= 0x4200)) atomicAdd(&cnt_sane, 1);
    if (threadIdx.x < 64) {
        if (ei[threadIdx.x * 2 + 1] != 0u) atomicAdd(&cnt_odd_nz, 1);
    }
    __syncthreads();
    if (threadIdx.x == 0) {
        flags[0] = (cnt_sane >= 192) ? 1 : 0;
        flags[1] = (cnt_odd_nz == 0) ? 1 : 0;
    }
}

// ---------- weight canonicalization -> fp32 ----------
__global__ void wconv_k(const int* __restrict__ flags,
                        const void* __restrict__ Wm, const void* __restrict__ Wu,
                        const void* __restrict__ bm, const void* __restrict__ bu,
                        const void* __restrict__ ga, const void* __restrict__ be,
                        float* __restrict__ WfM, float* __restrict__ WfU,
                        float* __restrict__ prm) {
    const int bf = flags[0];
    int i = blockIdx.x * 256 + threadIdx.x;
    if (i < 16384) {
        const void* src = (i < 8192) ? Wm : Wu;
        float* dst = (i < 8192) ? WfM : WfU;
        int ii = i & 8191, j = ii >> 6, k = ii & 63;
        int si = (j & 63) * 128 + ((j >> 6) ? 64 : 0) + k;
        dst[ii] = bf ? bf2f(((const unsigned short*)src)[si]) : ((const float*)src)[si];
    } else if (i < 16384 + 256) {
        int t = i - 16384, which = t >> 6, k = t & 63;
        const void* p = (which == 0) ? bm : (which == 1) ? bu : (which == 2) ? ga : be;
        prm[t] = bf ? bf2f(((const unsigned short*)p)[k]) : ((const float*)p)[k];
    }
}

// ---------- projection: Ps = x@Wm_s^T ; Pt = x@Wm_t^T + b_msg  (bf16 out) ----------
__global__ __launch_bounds__(256) void proj_k(const int* __restrict__ flags,
                                              const void* __restrict__ xv,
                                              const float* __restrict__ WfM,
                                              const float* __restrict__ prm,
                                              __hip_bfloat16* __restrict__ Ps,
                                              __hip_bfloat16* __restrict__ Pt) {
    const int bf = flags[0];
    const int lane = threadIdx.x & 63;
    const int wib = __builtin_amdgcn_readfirstlane(threadIdx.x >> 6);

    float wsr[64], wtr[64];
    {
        const float* r0 = WfM + lane * 64;
        const float* r1 = WfM + (64 + lane) * 64;
        #pragma unroll
        for (int k = 0; k < 64; ++k) { wsr[k] = r0[k]; wtr[k] = r1[k]; }
    }
    const float bm = prm[lane];

    for (int n = blockIdx.x * 4 + wib; n < NNODES; n += gridDim.x * 4) {
        float as0 = 0.f, as1 = 0.f, at0 = 0.f, at1 = 0.f;
        if (bf) {
            const uint32_t* xw = (const uint32_t*)((const unsigned short*)xv + (size_t)n * DF);
            #pragma unroll
            for (int d = 0; d < 32; ++d) {
                float x0, x1; unpack2(xw[d], x0, x1);
                as0 = fmaf(x0, wsr[2*d],   as0);
                as1 = fmaf(x1, wsr[2*d+1], as1);
                at0 = fmaf(x0, wtr[2*d],   at0);
                at1 = fmaf(x1, wtr[2*d+1], at1);
            }
        } else {
            const float* xf = (const float*)xv + (size_t)n * DF;
            #pragma unroll
            for (int d = 0; d < 64; d += 2) {
                as0 = fmaf(xf[d],   wsr[d],   as0);
                as1 = fmaf(xf[d+1], wsr[d+1], as1);
                at0 = fmaf(xf[d],   wtr[d],   at0);
                at1 = fmaf(xf[d+1], wtr[d+1], at1);
            }
        }
        Ps[(size_t)n * DF + lane] = __float2bfloat16(as0 + as1);
        Pt[(size_t)n * DF + lane] = __float2bfloat16(at0 + at1 + bm);
    }
}

// ---------- bucket histogram (LDS pre-aggregated) ----------
__global__ __launch_bounds__(256) void bhist_k(const int* __restrict__ flags,
                                               const int* __restrict__ ei,
                                               int* __restrict__ BktCnt) {
    __shared__ int h[NBUCK];
    const int i64 = flags[1];
    for (int i = threadIdx.x; i < NBUCK; i += 256) h[i] = 0;
    __syncthreads();
    int stride = gridDim.x * 256;
    for (int e = blockIdx.x * 256 + threadIdx.x; e < NEDGES; e += stride) {
        int tgt = i64 ? ei[4*e + 2] : ei[2*e + 1];
        if ((unsigned)tgt < NNODES) atomicAdd(&h[tgt / BKT], 1);
    }
    __syncthreads();
    for (int b = threadIdx.x; b < NBUCK; b += 256)
        if (h[b]) atomicAdd(BktCnt + b, h[b]);
}

// ---------- scan of 1000 bucket counts ----------
__global__ __launch_bounds__(1024) void bscan_k(const int* __restrict__ BktCnt,
                                                int* __restrict__ BktOff,
                                                int* __restrict__ BktCur) {
    __shared__ int lds[1024];
    int t = threadIdx.x;
    int c = (t < NBUCK) ? BktCnt[t] : 0;
    lds[t] = c;
    __syncthreads();
    for (int off = 1; off < 1024; off <<= 1) {
        int add = (t >= off) ? lds[t - off] : 0;
        __syncthreads();
        lds[t] += add;
        __syncthreads();
    }
    if (t < NBUCK) {
        int ex = lds[t] - c;
        BktOff[t] = ex;
        BktCur[t] = ex;
    }
    if (t == NBUCK - 1) BktOff[NBUCK] = lds[t];
}

// ---------- bucket fill: two-pass binning, packed (tl<<24 | src) ----------
__global__ __launch_bounds__(256) void bfill_k(const int* __restrict__ flags,
                                               const int* __restrict__ ei,
                                               int* __restrict__ BktCur,
                                               int* __restrict__ BktE) {
    __shared__ int h[NBUCK], h2[NBUCK], basee[NBUCK];
    const int i64 = flags[1];
    for (int i = threadIdx.x; i < NBUCK; i += 256) { h[i] = 0; h2[i] = 0; }
    __syncthreads();
    const int stride = gridDim.x * 256;
    for (int e = blockIdx.x * 256 + threadIdx.x; e < NEDGES; e += stride) {
        int tgt = i64 ? ei[4*e + 2] : ei[2*e + 1];
        if ((unsigned)tgt < NNODES) atomicAdd(&h[tgt / BKT], 1);
    }
    __syncthreads();
    for (int b = threadIdx.x; b < NBUCK; b += 256)
        if (h[b]) basee[b] = atomicAdd(BktCur + b, h[b]);
    __syncthreads();
    for (int e = blockIdx.x * 256 + threadIdx.x; e < NEDGES; e += stride) {
        int src, tgt;
        if (i64) { src = ei[4*e]; tgt = ei[4*e + 2]; }
        else     { src = ei[2*e]; tgt = ei[2*e + 1]; }
        if ((unsigned)tgt >= NNODES) continue;
        int b = tgt / BKT;
        int tl = tgt - b * BKT;
        int r = atomicAdd(&h2[b], 1);
        BktE[basee[b] + r] = (tl << 24) | (src & 0xFFFFFF);
    }
}

// ---------- per-bucket counting sort by target -> CsrSrc + Row ----------
// block b owns BktE[s..e) and CsrSrc[s..e) (its own contiguous region).
__global__ __launch_bounds__(256) void tsort_k(const int* __restrict__ BktOff,
                                               const int* __restrict__ BktE,
                                               int* __restrict__ CsrSrc,
                                               int* __restrict__ Row) {
    __shared__ int oc[128], excl[128], cur[128];
    const int tid = threadIdx.x;
    const int b = blockIdx.x;
    const int s = BktOff[b], e = BktOff[b + 1];
    const int n = e - s;
    if (tid < 128) { oc[tid] = 0; }
    __syncthreads();
    for (int i = tid; i < n; i += 256)
        atomicAdd(&oc[((unsigned)BktE[s + i]) >> 24], 1);
    __syncthreads();
    // exclusive scan of oc[0..127] (shift then Hillis-Steele inclusive)
    if (tid < 128) excl[tid] = (tid > 0) ? oc[tid - 1] : 0;
    __syncthreads();
    for (int off = 1; off < 128; off <<= 1) {
        int add = (tid >= off && tid < 128) ? excl[tid - off] : 0;
        __syncthreads();
        if (tid < 128) excl[tid] += add;
        __syncthreads();
    }
    if (tid < BKT) {
        Row[b * BKT + tid] = s + excl[tid];
        cur[tid] = excl[tid];
    }
    if (b == 0 && tid == 0) Row[NNODES] = NEDGES;
    __syncthreads();
    for (int i = tid; i < n; i += 256) {
        int v = BktE[s + i];
        int tl = ((unsigned)v) >> 24;
        int p = atomicAdd(&cur[tl], 1);
        CsrSrc[s + p] = v & 0xFFFFFF;
    }
}

// ---------- aggregation: target-aligned chunks, register accumulate ----------
// wave w owns all targets whose segment START lies in [w*CHUNK, (w+1)*CHUNK)
// -> each target written by exactly one wave; plain bf16 store, mean fused.
__global__ __launch_bounds__(256) void agg_k(const __hip_bfloat16* __restrict__ Ps,
                                             const __hip_bfloat16* __restrict__ Pt,
                                             const int* __restrict__ Row,
                                             const int* __restrict__ CsrSrc,
                                             __hip_bfloat16* __restrict__ Msg) {
    const int lane = threadIdx.x & 63;
    const int wib = __builtin_amdgcn_readfirstlane(threadIdx.x >> 6);
    const int w = blockIdx.x * 4 + wib;
    if (w >= NCHUNK) return;
    const int eA = w * CHUNK;
    const int hiB = (w == NCHUNK - 1) ? (NEDGES + 1) : (eA + CHUNK);

    // t_lo = first t with Row[t] >= eA ; t_hi = first t with Row[t] >= hiB
    int lo = 0, hi = NNODES + 1;
    while (lo < hi) { int mid = (lo + hi) >> 1; if (Row[mid] >= eA) hi = mid; else lo = mid + 1; }
    const int t_lo = lo;
    lo = t_lo; hi = NNODES + 1;
    while (lo < hi) { int mid = (lo + hi) >> 1; if (Row[mid] >= hiB) hi = mid; else lo = mid + 1; }
    int t_hi = lo;
    if (t_hi > NNODES) t_hi = NNODES;

    const unsigned short* Ps16 = (const unsigned short*)Ps;
    const unsigned short* Pt16 = (const unsigned short*)Pt;

    for (int t = t_lo; t < t_hi; ++t) {
        const int segS = Row[t], segE = Row[t + 1];
        const int deg = segE - segS;
        float pt = bf2f(Pt16[(size_t)t * DF + lane]);
        float macc = 0.f;
        int i = segS;
        for (; i + 8 <= segE; i += 8) {
            int s0 = CsrSrc[i+0], s1 = CsrSrc[i+1], s2 = CsrSrc[i+2], s3 = CsrSrc[i+3];
            int s4 = CsrSrc[i+4], s5 = CsrSrc[i+5], s6 = CsrSrc[i+6], s7 = CsrSrc[i+7];
            if ((unsigned)s0 >= NNODES) s0 = 0;
            if ((unsigned)s1 >= NNODES) s1 = 0;
            if ((unsigned)s2 >= NNODES) s2 = 0;
            if ((unsigned)s3 >= NNODES) s3 = 0;
            if ((unsigned)s4 >= NNODES) s4 = 0;
            if ((unsigned)s5 >= NNODES) s5 = 0;
            if ((unsigned)s6 >= NNODES) s6 = 0;
            if ((unsigned)s7 >= NNODES) s7 = 0;
            float p0 = bf2f(Ps16[(size_t)s0 * DF + lane]);
            float p1 = bf2f(Ps16[(size_t)s1 * DF + lane]);
            float p2 = bf2f(Ps16[(size_t)s2 * DF + lane]);
            float p3 = bf2f(Ps16[(size_t)s3 * DF + lane]);
            float p4 = bf2f(Ps16[(size_t)s4 * DF + lane]);
            float p5 = bf2f(Ps16[(size_t)s5 * DF + lane]);
            float p6 = bf2f(Ps16[(size_t)s6 * DF + lane]);
            float p7 = bf2f(Ps16[(size_t)s7 * DF + lane]);
            macc += fmaxf(p0 + pt, 0.f) + fmaxf(p1 + pt, 0.f)
                  + fmaxf(p2 + pt, 0.f) + fmaxf(p3 + pt, 0.f)
                  + fmaxf(p4 + pt, 0.f) + fmaxf(p5 + pt, 0.f)
                  + fmaxf(p6 + pt, 0.f) + fmaxf(p7 + pt, 0.f);
        }
        for (; i < segE; ++i) {
            int s0 = CsrSrc[i];
            if ((unsigned)s0 >= NNODES) s0 = 0;
            macc += fmaxf(bf2f(Ps16[(size_t)s0 * DF + lane]) + pt, 0.f);
        }
        float mval = (deg > 0) ? (macc / (float)deg) : 0.f;
        Msg[(size_t)t * DF + lane] = __float2bfloat16(mval);
    }
}

// ---------- update + residual + LayerNorm ----------
__global__ __launch_bounds__(256) void upd_k(const int* __restrict__ flags,
                                             const void* __restrict__ xv,
                                             const __hip_bfloat16* __restrict__ Msg,
                                             const float* __restrict__ WfU,
                                             const float* __restrict__ prm,
                                             void* __restrict__ outv) {
    const int bf = flags[0];
    const int lane = threadIdx.x & 63;
    const int wib = __builtin_amdgcn_readfirstlane(threadIdx.x >> 6);

    float wx[64], wm[64];
    {
        const float* r0 = WfU + lane * 64;
        const float* r1 = WfU + (lane + 64) * 64;
        #pragma unroll
        for (int k = 0; k < 64; ++k) { wx[k] = r0[k]; wm[k] = r1[k]; }
    }
    const float bu = prm[64 + lane];
    const float ga = prm[128 + lane];
    const float be = prm[192 + lane];

    for (int n = blockIdx.x * 4 + wib; n < NNODES; n += gridDim.x * 4) {
        float da0 = 0.f, da1 = 0.f, db0 = 0.f, db1 = 0.f;
        float xl;
        if (bf) {
            const uint32_t* xw = (const uint32_t*)((const unsigned short*)xv + (size_t)n * DF);
            #pragma unroll
            for (int d = 0; d < 32; ++d) {
                float x0, x1; unpack2(xw[d], x0, x1);
                da0 = fmaf(x0, wx[2*d],   da0);
                da1 = fmaf(x1, wx[2*d+1], da1);
            }
            xl = bf2f(((const unsigned short*)xv)[(size_t)n * DF + lane]);
        } else {
            const float* xf = (const float*)xv + (size_t)n * DF;
            #pragma unroll
            for (int d = 0; d < 64; d += 2) {
                da0 = fmaf(xf[d],   wx[d],   da0);
                da1 = fmaf(xf[d+1], wx[d+1], da1);
            }
            xl = ((const float*)xv)[(size_t)n * DF + lane];
        }
        {
            const uint32_t* mw = (const uint32_t*)((const unsigned short*)Msg + (size_t)n * DF);
            #pragma unroll
            for (int d = 0; d < 32; ++d) {
                float m0, m1; unpack2(mw[d], m0, m1);
                db0 = fmaf(m0, wm[2*d],   db0);
                db1 = fmaf(m1, wm[2*d+1], db1);
            }
        }
        float u = fmaxf((da0 + da1) + (db0 + db1) + bu, 0.f);
        float r = u + xl;

        float s = r, s2 = r * r;
        #pragma unroll
        for (int m = 1; m < 64; m <<= 1) {
            s  += __shfl_xor(s, m, 64);
            s2 += __shfl_xor(s2, m, 64);
        }
        float mu  = s * (1.0f / 64.0f);
        float var = fmaxf(s2 * (1.0f / 64.0f) - mu * mu, 0.f);
        float o = (r - mu) * rsqrtf(var + 1e-5f) * ga + be;

        size_t gi = (size_t)n * DF + lane;
        if (bf) ((__hip_bfloat16*)outv)[gi] = __float2bfloat16(o);
        else    ((float*)outv)[gi] = o;
    }
}

extern "C" void kernel_launch(void* const* d_in, const int* in_sizes, int n_in,
                              void* d_out, int out_size, void* d_ws, size_t ws_size,
                              hipStream_t stream) {
    const void* x  = d_in[0];
    const int*  ei = (const int*)d_in[1];
    const void* Wm = d_in[2];
    const void* bm = d_in[3];
    const void* Wu = d_in[4];
    const void* bu = d_in[5];
    const void* ga = d_in[6];
    const void* be = d_in[7];

    char* ws = (char*)d_ws;
    size_t off = 0;
    __hip_bfloat16* Ps  = (__hip_bfloat16*)(ws + off); off += (size_t)ND * 2;   // 12.8 MB
    __hip_bfloat16* Pt  = (__hip_bfloat16*)(ws + off); off += (size_t)ND * 2;   // 12.8 MB
    __hip_bfloat16* Msg = (__hip_bfloat16*)(ws + off); off += (size_t)ND * 2;   // 12.8 MB
    int*   BktE   = (int*)(ws + off); off += (size_t)NEDGES * 4;                // 6.4 MB
    int*   CsrSrc = (int*)(ws + off); off += (size_t)NEDGES * 4;                // 6.4 MB
    int*   Row    = (int*)(ws + off); off += (size_t)(NNODES + 1) * 4;
    int*   BktCnt = (int*)(ws + off); off += NBUCK * 4;                         // memset 0
    int*   BktOff = (int*)(ws + off); off += (NBUCK + 1) * 4;
    int*   BktCur = (int*)(ws + off); off += NBUCK * 4;
    int*   flg    = (int*)(ws + off); off += 16;
    float* WfM    = (float*)(ws + off); off += 8192 * 4;
    float* WfU    = (float*)(ws + off); off += 8192 * 4;
    float* prm    = (float*)(ws + off); off += 256 * 4;
    // total = 51,678,584 bytes (< proven ws_size >= 51.7 MB)

    (void)hipMemsetAsync(BktCnt, 0, NBUCK * 4, stream);

    detect_k<<<1, 256, 0, stream>>>((const unsigned short*)x, (const unsigned int*)ei, flg);
    wconv_k<<<65, 256, 0, stream>>>(flg, Wm, Wu, bm, bu, ga, be, WfM, WfU, prm);

    proj_k<<<1563, 256, 0, stream>>>(flg, x, WfM, prm, Ps, Pt);

    bhist_k<<<256, 256, 0, stream>>>(flg, ei, BktCnt);
    bscan_k<<<1, 1024, 0, stream>>>(BktCnt, BktOff, BktCur);
    bfill_k<<<128, 256, 0, stream>>>(flg, ei, BktCur, BktE);
    tsort_k<<<NBUCK, 256, 0, stream>>>(BktOff, BktE, CsrSrc, Row);

    agg_k<<<(NCHUNK + 3) / 4, 256, 0, stream>>>(Ps, Pt, Row, CsrSrc, Msg);

    upd_k<<<1563, 256, 0, stream>>>(flg, x, Msg, WfU, prm, d_out);
}